// Round 4
// baseline (673.223 us; speedup 1.0000x reference)
//
#include <hip/hip_runtime.h>
#include <hip/hip_bf16.h>

#define N_ROWS 262144
#define DIM 64
#define KCODES 512
#define CHUNK 128
#define THREADS 256
#define ROWS_PER_BLOCK (THREADS * 2)            // 512 rows per argmin block
#define NBLOCKS (N_ROWS / ROWS_PER_BLOCK)       // 512
#define MARGIN_T 2.0e-5f                        // ~2.5 ulp(64) + fp32-dot noise

// d_out is FLOAT32. Flat layout in return order:
// [0] loss | [1 .. 1+N*D) quantized | [1+N*D] norm_perplexity | [2+N*D ..) indices
#define OFF_Q 1
#define OFF_PERP (1 + (size_t)N_ROWS * DIM)
#define OFF_IDX (2 + (size_t)N_ROWS * DIM)

// numpy pairwise sum of squares for n=64 (loops.c.src): 8 strided accumulators,
// sequential adds, fixed combine tree. contract(off): square rounds BEFORE add,
// exactly like numpy's tmp = v**2 ; np.sum(tmp).
__device__ __forceinline__ float np_sum_sq64(const float* __restrict__ v) {
#pragma clang fp contract(off)
    float r[8];
#pragma unroll
    for (int l = 0; l < 8; ++l) r[l] = v[l] * v[l];
#pragma unroll
    for (int k = 1; k < 8; ++k) {
#pragma unroll
        for (int l = 0; l < 8; ++l) {
            float sq = v[8 * k + l] * v[8 * k + l];
            r[l] = r[l] + sq;
        }
    }
    return ((r[0] + r[1]) + (r[2] + r[3])) + ((r[4] + r[5]) + (r[6] + r[7]));
}

// SSE of (W[best] - x) for the loss (loose threshold; plain fp32 is fine).
__device__ __forceinline__ float row_sse(const float* __restrict__ W, int best,
                                         const float (&x)[DIM]) {
    const float4* wr = (const float4*)(W + (size_t)best * DIM);
    float sse = 0.f;
#pragma unroll
    for (int i = 0; i < 16; ++i) {
        float4 v = wr[i];
        float d0 = v.x - x[4 * i + 0];
        float d1 = v.y - x[4 * i + 1];
        float d2 = v.z - x[4 * i + 2];
        float d3 = v.w - x[4 * i + 3];
        sse = fmaf(d0, d0, sse);
        sse = fmaf(d1, d1, sse);
        sse = fmaf(d2, d2, sse);
        sse = fmaf(d3, d3, sse);
    }
    return sse;
}

// Exact replication of numpy's fp32 distance for one (row, code):
// e = fp32( fp32(A + B_j) - fp32(2*dot) ), dot accurate via fp64.
__device__ __forceinline__ float np_e(const float* __restrict__ W, int idx,
                                      const float (&x)[DIM], float A, float Bj) {
#pragma clang fp contract(off)
    const float* w = W + (size_t)idx * DIM;
    double dot = 0.0;
#pragma unroll
    for (int d = 0; d < DIM; ++d) dot = fma((double)w[d], (double)x[d], dot);
    float C2 = (float)(2.0 * dot);
    float AB = A + Bj;
    return AB - C2;
}

// Resolve np-fp32 argmin among <=4 candidates within margin (first-index ties).
__device__ __forceinline__ int resolve(const float* __restrict__ W, const float (&x)[DIM],
                                       float A, const float* __restrict__ sB,
                                       float m1, float m2, float m3, float m4,
                                       int i1, int i2, int i3, int i4) {
    int nc = 1;
    if (m2 < m1 + MARGIN_T) nc = 2;
    if (m3 < m1 + MARGIN_T) nc = 3;
    if (m4 < m1 + MARGIN_T) nc = 4;
    if (nc == 1) return i1;
    int cand[4] = {i1, i2, i3, i4};
    int bi = cand[0];
    float be = np_e(W, bi, x, A, sB[bi]);
    for (int c = 1; c < nc; ++c) {
        int idx = cand[c];
        float e = np_e(W, idx, x, A, sB[idx]);
        if (e < be || (e == be && idx < bi)) { be = e; bi = idx; }
    }
    return bi;
}

__global__ __launch_bounds__(THREADS) void vq_argmin(
    const float* __restrict__ X, const float* __restrict__ W,
    float* __restrict__ out, float* __restrict__ sseAcc,
    unsigned* __restrict__ gHist) {
    __shared__ __align__(16) float sW[CHUNK * DIM]; // 32 KiB code chunk
    __shared__ float sB[KCODES];                    // numpy-pairwise ||w||^2
    __shared__ unsigned sHist[KCODES];
    __shared__ float sSse;

    const int tid = threadIdx.x;
    const int r0 = blockIdx.x * ROWS_PER_BLOCK + tid;
    const int r1 = r0 + THREADS;

    if (tid == 0) sSse = 0.f;
    sHist[tid] = 0u;
    sHist[tid + THREADS] = 0u;
    for (int k = tid; k < KCODES; k += THREADS)
        sB[k] = np_sum_sq64(W + (size_t)k * DIM);   // numpy summation order

    float x0[DIM], x1[DIM];
    {
        const float4* xr0 = (const float4*)(X + (size_t)r0 * DIM);
        const float4* xr1 = (const float4*)(X + (size_t)r1 * DIM);
#pragma unroll
        for (int i = 0; i < 16; ++i) {
            float4 v = xr0[i];
            x0[4 * i + 0] = v.x; x0[4 * i + 1] = v.y; x0[4 * i + 2] = v.z; x0[4 * i + 3] = v.w;
            float4 u = xr1[i];
            x1[4 * i + 0] = u.x; x1[4 * i + 1] = u.y; x1[4 * i + 2] = u.z; x1[4 * i + 3] = u.w;
        }
    }
    const float A0 = np_sum_sq64(x0);               // numpy summation order
    const float A1 = np_sum_sq64(x1);

    // top-4 by fast criterion t = B_j - 2*dot32 (sorted ascending)
    float m1_0 = 3.4e38f, m2_0 = 3.4e38f, m3_0 = 3.4e38f, m4_0 = 3.4e38f;
    int i1_0 = 0, i2_0 = 0, i3_0 = 0, i4_0 = 0;
    float m1_1 = 3.4e38f, m2_1 = 3.4e38f, m3_1 = 3.4e38f, m4_1 = 3.4e38f;
    int i1_1 = 0, i2_1 = 0, i3_1 = 0, i4_1 = 0;

    for (int c0 = 0; c0 < KCODES; c0 += CHUNK) {
        __syncthreads();
        {   // stage CHUNK codes into LDS (coalesced float4)
            const float4* g = (const float4*)(W + (size_t)c0 * DIM);
            float4* l = (float4*)sW;
#pragma unroll
            for (int i = 0; i < (CHUNK * DIM / 4) / THREADS; ++i)
                l[tid + THREADS * i] = g[tid + THREADS * i];
        }
        __syncthreads();

        for (int jj = 0; jj < CHUNK; ++jj) {
            const int j = c0 + jj;
            const float4* wv = (const float4*)(sW + jj * DIM);  // wave-uniform -> broadcast
            float a0 = 0.f, b0 = 0.f, a1 = 0.f, b1 = 0.f;
#pragma unroll
            for (int i = 0; i < 16; i += 2) {
                const float4 wA = wv[i];
                const float4 wB = wv[i + 1];
                a0 = fmaf(wA.x, x0[4 * i + 0], a0);
                a0 = fmaf(wA.y, x0[4 * i + 1], a0);
                a0 = fmaf(wA.z, x0[4 * i + 2], a0);
                a0 = fmaf(wA.w, x0[4 * i + 3], a0);
                a1 = fmaf(wA.x, x1[4 * i + 0], a1);
                a1 = fmaf(wA.y, x1[4 * i + 1], a1);
                a1 = fmaf(wA.z, x1[4 * i + 2], a1);
                a1 = fmaf(wA.w, x1[4 * i + 3], a1);
                b0 = fmaf(wB.x, x0[4 * i + 4], b0);
                b0 = fmaf(wB.y, x0[4 * i + 5], b0);
                b0 = fmaf(wB.z, x0[4 * i + 6], b0);
                b0 = fmaf(wB.w, x0[4 * i + 7], b0);
                b1 = fmaf(wB.x, x1[4 * i + 4], b1);
                b1 = fmaf(wB.y, x1[4 * i + 5], b1);
                b1 = fmaf(wB.z, x1[4 * i + 6], b1);
                b1 = fmaf(wB.w, x1[4 * i + 7], b1);
            }
            const float Bj = sB[j];
            const float t0 = fmaf(-2.f, a0 + b0, Bj);
            const float t1 = fmaf(-2.f, a1 + b1, Bj);
            {   // sorted top-4 insert, row 0 (strict < keeps first occurrence)
                bool l1 = t0 < m1_0, l2 = t0 < m2_0, l3 = t0 < m3_0, l4 = t0 < m4_0;
                m4_0 = l3 ? m3_0 : (l4 ? t0 : m4_0);  i4_0 = l3 ? i3_0 : (l4 ? j : i4_0);
                m3_0 = l2 ? m2_0 : (l3 ? t0 : m3_0);  i3_0 = l2 ? i2_0 : (l3 ? j : i3_0);
                m2_0 = l1 ? m1_0 : (l2 ? t0 : m2_0);  i2_0 = l1 ? i1_0 : (l2 ? j : i2_0);
                m1_0 = l1 ? t0 : m1_0;                i1_0 = l1 ? j : i1_0;
            }
            {   // row 1
                bool l1 = t1 < m1_1, l2 = t1 < m2_1, l3 = t1 < m3_1, l4 = t1 < m4_1;
                m4_1 = l3 ? m3_1 : (l4 ? t1 : m4_1);  i4_1 = l3 ? i3_1 : (l4 ? j : i4_1);
                m3_1 = l2 ? m2_1 : (l3 ? t1 : m3_1);  i3_1 = l2 ? i2_1 : (l3 ? j : i3_1);
                m2_1 = l1 ? m1_1 : (l2 ? t1 : m2_1);  i2_1 = l1 ? i1_1 : (l2 ? j : i2_1);
                m1_1 = l1 ? t1 : m1_1;                i1_1 = l1 ? j : i1_1;
            }
        }
    }

    const int best0 = resolve(W, x0, A0, sB, m1_0, m2_0, m3_0, m4_0, i1_0, i2_0, i3_0, i4_0);
    const int best1 = resolve(W, x1, A1, sB, m1_1, m2_1, m3_1, m4_1, i1_1, i2_1, i3_1, i4_1);

    out[OFF_IDX + r0] = (float)best0;
    out[OFF_IDX + r1] = (float)best1;

    const float sse0 = row_sse(W, best0, x0);
    const float sse1 = row_sse(W, best1, x1);

    atomicAdd(&sHist[best0], 1u);
    atomicAdd(&sHist[best1], 1u);

    float v = sse0 + sse1;
#pragma unroll
    for (int off = 32; off; off >>= 1) v += __shfl_down(v, off);
    if ((tid & 63) == 0) atomicAdd(&sSse, v);

    __syncthreads();
    for (int k = tid; k < KCODES; k += THREADS) {
        unsigned c = sHist[k];
        if (c) atomicAdd(&gHist[k], c);
    }
    if (tid == 0) atomicAdd(sseAcc, sSse);
}

// One wave per row: lanes 0..63 cover the 64 dims. Index load is wave-uniform,
// W gather is one coalesced 256B load (L2-hot), store coalesced.
__global__ __launch_bounds__(THREADS) void vq_scatter(
    const float* __restrict__ W, float* __restrict__ out) {
    const int gid = blockIdx.x * THREADS + threadIdx.x;
    const int row = gid >> 6;
    const int lane = gid & 63;
    int idx = (int)out[OFF_IDX + row];
    if ((unsigned)idx >= KCODES) idx = KCODES - 1;   // safety clamp
    out[OFF_Q + (size_t)row * DIM + lane] = W[(size_t)idx * DIM + lane];
}

__global__ __launch_bounds__(512) void vq_finalize(
    const float* __restrict__ sseAcc, const unsigned* __restrict__ gHist,
    float* __restrict__ out) {
    __shared__ float partial[8];
    const int t = threadIdx.x;
    float p = (float)gHist[t] * (1.0f / (float)N_ROWS);
    float v = p * logf(p + 1e-10f);
#pragma unroll
    for (int off = 32; off; off >>= 1) v += __shfl_down(v, off);
    if ((t & 63) == 0) partial[t >> 6] = v;
    __syncthreads();
    if (t == 0) {
        float s = 0.f;
#pragma unroll
        for (int i = 0; i < 8; ++i) s += partial[i];
        float norm_perp = expf(-s) * (1.0f / (float)KCODES);
        float loss = 1.25f * (sseAcc[0] * (1.0f / ((float)N_ROWS * (float)DIM)));
        out[0] = loss;
        out[OFF_PERP] = norm_perp;
    }
}

extern "C" void kernel_launch(void* const* d_in, const int* in_sizes, int n_in,
                              void* d_out, int out_size, void* d_ws, size_t ws_size,
                              hipStream_t stream) {
    const float* X = (const float*)d_in[0];
    const float* W = (const float*)d_in[1];
    float* out = (float*)d_out;
    float* sseAcc = (float*)d_ws;
    unsigned* gHist = (unsigned*)((char*)d_ws + 64);

    size_t zb = 64 + KCODES * sizeof(unsigned);     // 2112 B of ws used
    if (zb > ws_size) zb = ws_size;
    hipMemsetAsync(d_ws, 0, zb, stream);

    vq_argmin<<<NBLOCKS, THREADS, 0, stream>>>(X, W, out, sseAcc, gHist);
    vq_scatter<<<(N_ROWS * DIM) / THREADS, THREADS, 0, stream>>>(W, out);
    vq_finalize<<<1, 512, 0, stream>>>(sseAcc, gHist, out);
}